// Round 5
// baseline (200.346 us; speedup 1.0000x reference)
//
#include <hip/hip_runtime.h>
#include <hip/hip_bf16.h>
#include <math.h>

#define NN 4096
#define DD 128
#define CAPN 16
#define CAPM 16
#define NTILE 32   // 4096/128 column tiles per row
#define NB 528     // triangular 128x128 blocks

typedef _Float16 f16x8 __attribute__((ext_vector_type(8)));
typedef float f32x4 __attribute__((ext_vector_type(4)));

// ---------------------------------------------------------------------------
// f32 -> fp16 copies + sq norms from ROUNDED values; zero-init of
// revcnt/rowsum/acc (workspace is re-poisoned before every launch).
__global__ __launch_bounds__(64) void convert_kernel(
    const float* __restrict__ Xe, const float* __restrict__ Xz,
    _Float16* __restrict__ He, _Float16* __restrict__ Hz,
    float* __restrict__ sqe, float* __restrict__ sqz,
    int* __restrict__ revcnt, float* __restrict__ rowsum,
    double* __restrict__ acc) {
  int row = blockIdx.x;
  int lane = threadIdx.x;
  const float* X = blockIdx.y ? Xz : Xe;
  _Float16* H = blockIdx.y ? Hz : He;
  float* sq = blockIdx.y ? sqz : sqe;
  if (blockIdx.y == 0 && lane == 0) {
    revcnt[row] = 0;
    rowsum[row] = 0.0f;
    if (row < 256) acc[row] = 0.0;
  }
  float v0 = X[(size_t)row * DD + lane];
  float v1 = X[(size_t)row * DD + 64 + lane];
  _Float16 h0 = (_Float16)v0, h1 = (_Float16)v1;
  H[(size_t)row * DD + lane] = h0;
  H[(size_t)row * DD + 64 + lane] = h1;
  float f0 = (float)h0, f1 = (float)h1;
  float s = f0 * f0 + f1 * f1;
  for (int off = 32; off; off >>= 1) s += __shfl_down(s, off);
  if (lane == 0) sq[row] = s;
}

// ---------------------------------------------------------------------------
// passA: fp16 MFMA gram over triangular 128x128 blocks (bx<=by).
// mode 0 (z_ema): NO de store — emit per-(row,coltile) top-8 (value,index)
//                 candidates for the kth/mask computation.
// mode 1 (z):     dz fp16 store (tile+transpose via LDS, coalesced) + f32
//                 atomic row-sums of dz.
__global__ __launch_bounds__(256, 2) void passA_kernel(
    const _Float16* __restrict__ He, const float* __restrict__ sqe,
    const _Float16* __restrict__ Hz, const float* __restrict__ sqz,
    _Float16* __restrict__ dz, float* __restrict__ candv,
    int* __restrict__ candi, float* __restrict__ rowsum) {
  __shared__ char smem[65536];
  __shared__ float mbv[128][8];
  __shared__ int mbi[128][8];
  int b = blockIdx.x;
  int by = (int)((sqrtf(8.0f * (float)b + 1.0f) - 1.0f) * 0.5f);
  while ((by + 1) * (by + 2) / 2 <= b) by++;
  while (by * (by + 1) / 2 > b) by--;
  int bx = b - by * (by + 1) / 2;  // bx <= by
  int mode = blockIdx.z;
  const _Float16* H = mode ? Hz : He;
  const float* sq = mode ? sqz : sqe;
  int I = bx * 128, J = by * 128;
  int t = threadIdx.x;

  // stage 128 rows x 128 fp16 per side; XOR-swizzle byte ^= (row&7)<<4
#pragma unroll
  for (int it = 0; it < 8; ++it) {
    int u = it * 256 + t;
    int r = u >> 4, c16 = u & 15;
    int byteoff = r * 256 + ((c16 * 16) ^ ((r & 7) << 4));
    *reinterpret_cast<float4*>(smem + byteoff) =
        *reinterpret_cast<const float4*>(H + (size_t)(I + r) * DD + c16 * 8);
    *reinterpret_cast<float4*>(smem + 32768 + byteoff) =
        *reinterpret_cast<const float4*>(H + (size_t)(J + r) * DD + c16 * 8);
  }
  __syncthreads();

  int w = t >> 6, l = t & 63;
  int wr = (w >> 1) * 64, wc = (w & 1) * 64;
  f32x4 acc[4][4];
#pragma unroll
  for (int m = 0; m < 4; ++m)
#pragma unroll
    for (int n = 0; n < 4; ++n) {
      f32x4 zz = {0.f, 0.f, 0.f, 0.f};
      acc[m][n] = zz;
    }

#pragma unroll
  for (int kstep = 0; kstep < 4; ++kstep) {
    f16x8 a[4], bb[4];
    int colb = kstep * 64 + (l >> 4) * 16;
#pragma unroll
    for (int m = 0; m < 4; ++m) {
      int rr = wr + m * 16 + (l & 15);
      a[m] = *reinterpret_cast<const f16x8*>(smem + rr * 256 + (colb ^ ((rr & 7) << 4)));
    }
#pragma unroll
    for (int n = 0; n < 4; ++n) {
      int rr = wc + n * 16 + (l & 15);
      bb[n] = *reinterpret_cast<const f16x8*>(smem + 32768 + rr * 256 + (colb ^ ((rr & 7) << 4)));
    }
#pragma unroll
    for (int m = 0; m < 4; ++m)
#pragma unroll
      for (int n = 0; n < 4; ++n)
        acc[m][n] = __builtin_amdgcn_mfma_f32_16x16x32_f16(a[m], bb[n], acc[m][n], 0, 0, 0);
  }
  __syncthreads();  // staging reads done; reuse smem

  if (mode == 0) {
    // ---- write f32 distance tile to LDS (swizzled)
#pragma unroll
    for (int m = 0; m < 4; ++m) {
#pragma unroll
      for (int n = 0; n < 4; ++n) {
#pragma unroll
        for (int q = 0; q < 4; ++q) {
          int rt = wr + m * 16 + (l >> 4) * 4 + q;
          int ct = wc + n * 16 + (l & 15);
          int grow = I + rt, gcol = J + ct;
          float d2 = (grow == gcol) ? 0.0f : (sq[grow] + sq[gcol] - 2.0f * acc[m][n][q]);
          float d = __builtin_amdgcn_sqrtf(fmaxf(d2, 0.0f) + 1e-12f);
          *reinterpret_cast<float*>(smem + rt * 512 + ((ct * 4) ^ ((rt & 7) << 4))) = d;
        }
      }
    }
    __syncthreads();
    // ---- row scan: top-8 per tile-row
    {
      int row = t >> 1, h = t & 1;
      float bv[8]; int bi[8];
#pragma unroll
      for (int q = 0; q < 8; ++q) { bv[q] = 3.4e38f; bi[q] = -1; }
      for (int s4 = 0; s4 < 16; ++s4) {
        int c0 = h * 64 + s4 * 4;
        float4 v4 = *reinterpret_cast<const float4*>(
            smem + row * 512 + ((c0 * 4) ^ ((row & 7) << 4)));
        float vv[4] = {v4.x, v4.y, v4.z, v4.w};
#pragma unroll
        for (int e = 0; e < 4; ++e) {
          float v = vv[e];
          if (v < bv[7]) {
            bv[7] = v; bi[7] = J + c0 + e;
#pragma unroll
            for (int q = 7; q > 0; --q)
              if (bv[q] < bv[q - 1]) {
                float tv = bv[q]; bv[q] = bv[q - 1]; bv[q - 1] = tv;
                int ti = bi[q]; bi[q] = bi[q - 1]; bi[q - 1] = ti;
              }
          }
        }
      }
      if (h == 1) {
#pragma unroll
        for (int q = 0; q < 8; ++q) { mbv[row][q] = bv[q]; mbi[row][q] = bi[q]; }
      }
      __syncthreads();
      if (h == 0) {
        float ov[8]; int oi[8];
        int ia = 0, ib = 0;
#pragma unroll
        for (int q = 0; q < 8; ++q) {
          if (bv[ia] <= mbv[row][ib]) { ov[q] = bv[ia]; oi[q] = bi[ia]; ia++; }
          else { ov[q] = mbv[row][ib]; oi[q] = mbi[row][ib]; ib++; }
        }
        size_t base = ((size_t)(I + row) * NTILE + by) * 8;
#pragma unroll
        for (int q = 0; q < 8; ++q) { candv[base + q] = ov[q]; candi[base + q] = oi[q]; }
      }
      __syncthreads();
    }
    // ---- column scan (off-diagonal tiles): top-8 per tile-column
    if (bx != by) {
      int col = t >> 1, h = t & 1;
      float bv[8]; int bi[8];
#pragma unroll
      for (int q = 0; q < 8; ++q) { bv[q] = 3.4e38f; bi[q] = -1; }
      for (int s = 0; s < 64; ++s) {
        int rt = h * 64 + s;
        float v = *reinterpret_cast<const float*>(
            smem + rt * 512 + ((col * 4) ^ ((rt & 7) << 4)));
        if (v < bv[7]) {
          bv[7] = v; bi[7] = I + rt;
#pragma unroll
          for (int q = 7; q > 0; --q)
            if (bv[q] < bv[q - 1]) {
              float tv = bv[q]; bv[q] = bv[q - 1]; bv[q - 1] = tv;
              int ti = bi[q]; bi[q] = bi[q - 1]; bi[q - 1] = ti;
            }
        }
      }
      if (h == 1) {
#pragma unroll
        for (int q = 0; q < 8; ++q) { mbv[col][q] = bv[q]; mbi[col][q] = bi[q]; }
      }
      __syncthreads();
      if (h == 0) {
        float ov[8]; int oi[8];
        int ia = 0, ib = 0;
#pragma unroll
        for (int q = 0; q < 8; ++q) {
          if (bv[ia] <= mbv[col][ib]) { ov[q] = bv[ia]; oi[q] = bi[ia]; ia++; }
          else { ov[q] = mbv[col][ib]; oi[q] = mbi[col][ib]; ib++; }
        }
        size_t base = ((size_t)(J + col) * NTILE + bx) * 8;
#pragma unroll
        for (int q = 0; q < 8; ++q) { candv[base + q] = ov[q]; candi[base + q] = oi[q]; }
      }
    }
  } else {
    // ---- dz (fp16): tile + transpose staged in LDS, coalesced writes
#pragma unroll
    for (int m = 0; m < 4; ++m) {
#pragma unroll
      for (int n = 0; n < 4; ++n) {
#pragma unroll
        for (int q = 0; q < 4; ++q) {
          int rt = wr + m * 16 + (l >> 4) * 4 + q;
          int ct = wc + n * 16 + (l & 15);
          int grow = I + rt, gcol = J + ct;
          float d2 = (grow == gcol) ? 0.0f : (sq[grow] + sq[gcol] - 2.0f * acc[m][n][q]);
          float d = __builtin_amdgcn_sqrtf(fmaxf(d2, 0.0f) + 1e-12f);
          d = __builtin_amdgcn_sqrtf(d + 1e-9f);
          _Float16 h = (_Float16)d;
          *reinterpret_cast<_Float16*>(smem + rt * 256 + ((ct * 2) ^ ((rt & 7) << 4))) = h;
          if (bx != by)
            *reinterpret_cast<_Float16*>(smem + 32768 + ct * 256 + ((rt * 2) ^ ((ct & 7) << 4))) = h;
        }
      }
    }
    __syncthreads();
    for (int u = t; u < 128 * 16; u += 256) {
      int r = u >> 4, cg = u & 15;
      float4 v = *reinterpret_cast<const float4*>(
          smem + r * 256 + ((cg * 16) ^ ((r & 7) << 4)));
      *reinterpret_cast<float4*>((char*)dz + ((size_t)(I + r) * NN + J) * 2 + cg * 16) = v;
      if (bx != by) {
        float4 v2 = *reinterpret_cast<const float4*>(
            smem + 32768 + r * 256 + ((cg * 16) ^ ((r & 7) << 4)));
        *reinterpret_cast<float4*>((char*)dz + ((size_t)(J + r) * NN + I) * 2 + cg * 16) = v2;
      }
    }
    // ---- partial row sums (rows I+... from T; rows J+... from TT)
    {
      int row = t >> 1, h = t & 1;
      float s = 0.0f;
      for (int s4 = 0; s4 < 8; ++s4) {
        int c0 = h * 64 + s4 * 8;
        float4 v = *reinterpret_cast<const float4*>(
            smem + row * 256 + ((c0 * 2) ^ ((row & 7) << 4)));
        const _Float16* hp = reinterpret_cast<const _Float16*>(&v);
#pragma unroll
        for (int e = 0; e < 8; ++e) s += (float)hp[e];
      }
      s += __shfl_xor(s, 1);
      if (h == 0) atomicAdd(&rowsum[I + row], s);
      if (bx != by) {
        float s2 = 0.0f;
        for (int s4 = 0; s4 < 8; ++s4) {
          int c0 = h * 64 + s4 * 8;
          float4 v = *reinterpret_cast<const float4*>(
              smem + 32768 + row * 256 + ((c0 * 2) ^ ((row & 7) << 4)));
          const _Float16* hp = reinterpret_cast<const _Float16*>(&v);
#pragma unroll
          for (int e = 0; e < 8; ++e) s2 += (float)hp[e];
        }
        s2 += __shfl_xor(s2, 1);
        if (h == 0) atomicAdd(&rowsum[J + row], s2);
      }
    }
  }
}

// ---------------------------------------------------------------------------
// per-row: merge 32x8 candidates -> kth (5th smallest), nbr list, revcnt,
// and rminv = NN / rowsum.
__global__ __launch_bounds__(64) void rowfinal_kernel(
    const float* __restrict__ candv, const int* __restrict__ candi,
    const float* __restrict__ rowsum, float* __restrict__ rminv,
    int* __restrict__ nbr, int* __restrict__ nbrcnt, int* __restrict__ revcnt) {
  __shared__ int cnt;
  int row = blockIdx.x, lane = threadIdx.x;
  if (lane == 0) cnt = 0;
  size_t base = (size_t)row * NTILE * 8;
  float lv[4]; int li[4];
#pragma unroll
  for (int q = 0; q < 4; ++q) {
    lv[q] = candv[base + lane * 4 + q];
    li[q] = candi[base + lane * 4 + q];
  }
  // build local sorted-5 (pad inf)
  float m5[5] = {3.4e38f, 3.4e38f, 3.4e38f, 3.4e38f, 3.4e38f};
#pragma unroll
  for (int q = 0; q < 4; ++q) {
    float v = lv[q];
    if (v < m5[4]) {
      m5[4] = v;
#pragma unroll
      for (int p = 4; p > 0; --p)
        if (m5[p] < m5[p - 1]) { float tv = m5[p]; m5[p] = m5[p - 1]; m5[p - 1] = tv; }
    }
  }
  // butterfly merge of sorted-5 lists
#pragma unroll
  for (int mask = 1; mask < 64; mask <<= 1) {
    float o5[5];
#pragma unroll
    for (int q = 0; q < 5; ++q) o5[q] = __shfl_xor(m5[q], mask);
    float r5[5];
    int ia = 0, ib = 0;
#pragma unroll
    for (int q = 0; q < 5; ++q)
      r5[q] = (m5[ia] <= o5[ib]) ? m5[ia++] : o5[ib++];
#pragma unroll
    for (int q = 0; q < 5; ++q) m5[q] = r5[q];
  }
  float kth = m5[4];
  __syncthreads();
#pragma unroll
  for (int q = 0; q < 4; ++q) {
    if (lv[q] <= kth) {
      int p = atomicAdd(&cnt, 1);
      if (p < CAPN) nbr[row * CAPN + p] = li[q];
      atomicAdd(&revcnt[li[q]], 1);
    }
  }
  __syncthreads();
  if (lane == 0) {
    nbrcnt[row] = min(cnt, CAPN);
    rminv[row] = (float)NN / rowsum[row];
  }
}

// ---------------------------------------------------------------------------
// mutual lists: mut[k] = {j : j in kNN(k) and k in kNN(j)}
__global__ __launch_bounds__(64) void mut_kernel(
    const int* __restrict__ nbr, const int* __restrict__ nbrcnt,
    int* __restrict__ mut, int* __restrict__ mutcnt) {
  int k = blockIdx.x;
  int lane = threadIdx.x;
  __shared__ int cnt;
  if (lane == 0) cnt = 0;
  __syncthreads();
  int ck = nbrcnt[k];
  if (lane < ck) {
    int j = nbr[k * CAPN + lane];
    int cj = nbrcnt[j];
    bool found = false;
    for (int q = 0; q < cj; ++q)
      if (nbr[j * CAPN + q] == k) { found = true; break; }
    if (found) {
      int p = atomicAdd(&cnt, 1);
      if (p < CAPM) mut[k * CAPM + p] = j;
    }
  }
  __syncthreads();
  if (lane == 0) mutcnt[k] = min(cnt, CAPM);
}

// ---------------------------------------------------------------------------
// dense: recompute e-gram per triangular tile; stage dz tile from global;
// accumulate sum of 0.5*exp(-e)*a + relu(1-delta)^2 over BOTH orientations.
__global__ __launch_bounds__(256, 2) void dense_kernel(
    const _Float16* __restrict__ He, const float* __restrict__ sqe,
    const _Float16* __restrict__ dz, const float* __restrict__ rminv,
    double* __restrict__ acc) {
  __shared__ char smem[65536];
  __shared__ double red[256];
  int b = blockIdx.x;
  int by = (int)((sqrtf(8.0f * (float)b + 1.0f) - 1.0f) * 0.5f);
  while ((by + 1) * (by + 2) / 2 <= b) by++;
  while (by * (by + 1) / 2 > b) by--;
  int bx = b - by * (by + 1) / 2;  // bx <= by
  int I = bx * 128, J = by * 128;
  int t = threadIdx.x;

#pragma unroll
  for (int it = 0; it < 8; ++it) {
    int u = it * 256 + t;
    int r = u >> 4, c16 = u & 15;
    int byteoff = r * 256 + ((c16 * 16) ^ ((r & 7) << 4));
    *reinterpret_cast<float4*>(smem + byteoff) =
        *reinterpret_cast<const float4*>(He + (size_t)(I + r) * DD + c16 * 8);
    *reinterpret_cast<float4*>(smem + 32768 + byteoff) =
        *reinterpret_cast<const float4*>(He + (size_t)(J + r) * DD + c16 * 8);
  }
  __syncthreads();

  int w = t >> 6, l = t & 63;
  int wr = (w >> 1) * 64, wc = (w & 1) * 64;
  f32x4 acce[4][4];
#pragma unroll
  for (int m = 0; m < 4; ++m)
#pragma unroll
    for (int n = 0; n < 4; ++n) {
      f32x4 zz = {0.f, 0.f, 0.f, 0.f};
      acce[m][n] = zz;
    }

#pragma unroll
  for (int kstep = 0; kstep < 4; ++kstep) {
    f16x8 a[4], bb[4];
    int colb = kstep * 64 + (l >> 4) * 16;
#pragma unroll
    for (int m = 0; m < 4; ++m) {
      int rr = wr + m * 16 + (l & 15);
      a[m] = *reinterpret_cast<const f16x8*>(smem + rr * 256 + (colb ^ ((rr & 7) << 4)));
    }
#pragma unroll
    for (int n = 0; n < 4; ++n) {
      int rr = wc + n * 16 + (l & 15);
      bb[n] = *reinterpret_cast<const f16x8*>(smem + 32768 + rr * 256 + (colb ^ ((rr & 7) << 4)));
    }
#pragma unroll
    for (int m = 0; m < 4; ++m)
#pragma unroll
      for (int n = 0; n < 4; ++n)
        acce[m][n] = __builtin_amdgcn_mfma_f32_16x16x32_f16(a[m], bb[n], acce[m][n], 0, 0, 0);
  }
  __syncthreads();
  // stage dz tile (fp16, swizzled) into first 32 KB of smem
#pragma unroll
  for (int it = 0; it < 8; ++it) {
    int u = it * 256 + t;
    int r = u >> 4, c16 = u & 15;
    int byteoff = r * 256 + ((c16 * 16) ^ ((r & 7) << 4));
    *reinterpret_cast<float4*>(smem + byteoff) = *reinterpret_cast<const float4*>(
        (const char*)dz + ((size_t)(I + r) * NN + J) * 2 + c16 * 16);
  }
  __syncthreads();

  double s = 0.0;
  bool diag = (bx == by);
#pragma unroll
  for (int m = 0; m < 4; ++m) {
#pragma unroll
    for (int n = 0; n < 4; ++n) {
#pragma unroll
      for (int q = 0; q < 4; ++q) {
        int rt = wr + m * 16 + (l >> 4) * 4 + q;
        int ct = wc + n * 16 + (l & 15);
        if (diag && ct < rt) continue;
        int grow = I + rt, gcol = J + ct;
        float d2 = (grow == gcol) ? 0.0f : (sqe[grow] + sqe[gcol] - 2.0f * acce[m][n][q]);
        float e = __builtin_amdgcn_sqrtf(fmaxf(d2, 0.0f) + 1e-12f);
        float w2 = 0.5f * __expf(-e);
        float dzv = (float)*reinterpret_cast<const _Float16*>(
            smem + rt * 256 + ((ct * 2) ^ ((rt & 7) << 4)));
        float d1 = dzv * rminv[grow];
        float r1 = fmaxf(1.0f - d1, 0.0f);
        float a1 = d1 * d1 - r1 * r1;
        if (grow == gcol) {
          s += (double)(w2 * a1 + r1 * r1);
        } else {
          float d2v = dzv * rminv[gcol];
          float r2 = fmaxf(1.0f - d2v, 0.0f);
          float a2 = d2v * d2v - r2 * r2;
          s += (double)(w2 * (a1 + a2) + r1 * r1 + r2 * r2);
        }
      }
    }
  }
  red[t] = s;
  __syncthreads();
  for (int st = 128; st; st >>= 1) {
    if (t < st) red[t] += red[t + st];
    __syncthreads();
  }
  if (t == 0) atomicAdd(&acc[b & 127], red[0]);
}

// ---------------------------------------------------------------------------
// sparse: T = sum_l sum_{i,k in kNN(l)^2} c_i sum_{j in mut(k)} abar[i,j]
__global__ __launch_bounds__(64) void sparse_kernel(
    const int* __restrict__ nbr, const int* __restrict__ nbrcnt,
    const int* __restrict__ revcnt, const int* __restrict__ mut,
    const int* __restrict__ mutcnt, const _Float16* __restrict__ dz,
    const float* __restrict__ rminv, double* __restrict__ acc) {
  int l = blockIdx.x, lane = threadIdx.x;
  int cl = nbrcnt[l];
  int npairs = cl * cl;
  double s = 0.0;
  for (int p = lane; p < npairs; p += 64) {
    int i = nbr[l * CAPN + p / cl];
    int k = nbr[l * CAPN + p % cl];
    float ci = 1.0f / ((float)revcnt[i] * (float)mutcnt[i]);
    float inv_i = rminv[i];
    const _Float16* dzi = dz + (size_t)i * NN;
    int cm = mutcnt[k];
    float ps = 0.0f;
    for (int w2 = 0; w2 < cm; ++w2) {
      int j = mut[k * CAPM + w2];
      float dd = (float)dzi[j];
      float d1 = dd * inv_i;
      float d2v = dd * rminv[j];
      float r1 = fmaxf(1.0f - d1, 0.0f);
      float r2 = fmaxf(1.0f - d2v, 0.0f);
      ps += 0.5f * ((d1 * d1 - r1 * r1) + (d2v * d2v - r2 * r2));
    }
    s += (double)ci * (double)ps;
  }
  for (int off = 32; off; off >>= 1) s += __shfl_down(s, off);
  if (lane == 0) atomicAdd(&acc[128 + (l & 127)], s);
}

// ---------------------------------------------------------------------------
__global__ __launch_bounds__(256) void finalize_kernel(
    const double* __restrict__ acc, float* __restrict__ out) {
  __shared__ double red[256];
  int t = threadIdx.x;
  red[t] = acc[t] * ((t < 128) ? 1.0 : 0.5);
  __syncthreads();
  for (int st = 128; st; st >>= 1) {
    if (t < st) red[t] += red[t + st];
    __syncthreads();
  }
  if (t == 0) out[0] = (float)(red[0] / (double)NN);
}

// ---------------------------------------------------------------------------
extern "C" void kernel_launch(void* const* d_in, const int* in_sizes, int n_in,
                              void* d_out, int out_size, void* d_ws, size_t ws_size,
                              hipStream_t stream) {
  const float* z  = (const float*)d_in[0];
  const float* ze = (const float*)d_in[1];
  float* out = (float*)d_out;

  char* w = (char*)d_ws;
  size_t off = 0;
  _Float16* dz = (_Float16*)(w + off); off += (size_t)NN * NN * 2;  // 32 MiB
  float* candv = (float*)(w + off); off += (size_t)NN * NTILE * 8 * 4;  // 4 MiB
  int* candi = (int*)(w + off); off += (size_t)NN * NTILE * 8 * 4;      // 4 MiB
  _Float16* He = (_Float16*)(w + off); off += (size_t)NN * DD * 2;
  _Float16* Hz = (_Float16*)(w + off); off += (size_t)NN * DD * 2;
  float* sqe = (float*)(w + off); off += NN * 4;
  float* sqz = (float*)(w + off); off += NN * 4;
  float* rowsum = (float*)(w + off); off += NN * 4;
  float* rminv = (float*)(w + off); off += NN * 4;
  double* acc = (double*)(w + off); off += 256 * 8;
  int* nbrcnt = (int*)(w + off); off += NN * 4;
  int* mutcnt = (int*)(w + off); off += NN * 4;
  int* revcnt = (int*)(w + off); off += NN * 4;
  int* nbr = (int*)(w + off); off += (size_t)NN * CAPN * 4;
  int* mutl = (int*)(w + off); off += (size_t)NN * CAPM * 4;

  convert_kernel<<<dim3(NN, 2), 64, 0, stream>>>(ze, z, He, Hz, sqe, sqz,
                                                 revcnt, rowsum, acc);
  passA_kernel<<<dim3(NB, 1, 2), 256, 0, stream>>>(He, sqe, Hz, sqz, dz,
                                                   candv, candi, rowsum);
  rowfinal_kernel<<<NN, 64, 0, stream>>>(candv, candi, rowsum, rminv,
                                         nbr, nbrcnt, revcnt);
  mut_kernel<<<NN, 64, 0, stream>>>(nbr, nbrcnt, mutl, mutcnt);
  dense_kernel<<<NB, 256, 0, stream>>>(He, sqe, dz, rminv, acc);
  sparse_kernel<<<NN, 64, 0, stream>>>(nbr, nbrcnt, revcnt, mutl, mutcnt,
                                       dz, rminv, acc);
  finalize_kernel<<<1, 256, 0, stream>>>(acc, out);
}

// Round 12
// 168.558 us; speedup vs baseline: 1.1886x; 1.1886x over previous
//
#include <hip/hip_runtime.h>
#include <hip/hip_bf16.h>
#include <math.h>

#define NN 4096
#define DD 128
#define CAPN 16
#define CAPM 16
#define NB 528     // triangular 128x128 blocks

typedef _Float16 f16x8 __attribute__((ext_vector_type(8)));
typedef float f32x4 __attribute__((ext_vector_type(4)));

// ---------------------------------------------------------------------------
// f32 -> fp16 copies + sq norms from the ROUNDED values; zero-inits
// revcnt/rowsum/acc (workspace is re-poisoned before every launch).
__global__ __launch_bounds__(64) void convert_kernel(
    const float* __restrict__ Xe, const float* __restrict__ Xz,
    _Float16* __restrict__ He, _Float16* __restrict__ Hz,
    float* __restrict__ sqe, float* __restrict__ sqz,
    int* __restrict__ revcnt, float* __restrict__ rowsum,
    double* __restrict__ acc) {
  int row = blockIdx.x;
  int lane = threadIdx.x;
  const float* X = blockIdx.y ? Xz : Xe;
  _Float16* H = blockIdx.y ? Hz : He;
  float* sq = blockIdx.y ? sqz : sqe;
  if (blockIdx.y == 0 && lane == 0) {
    revcnt[row] = 0;
    rowsum[row] = 0.0f;
    if (row < 256) acc[row] = 0.0;
  }
  float v0 = X[(size_t)row * DD + lane];
  float v1 = X[(size_t)row * DD + 64 + lane];
  _Float16 h0 = (_Float16)v0, h1 = (_Float16)v1;
  H[(size_t)row * DD + lane] = h0;
  H[(size_t)row * DD + 64 + lane] = h1;
  float f0 = (float)h0, f1 = (float)h1;
  float s = f0 * f0 + f1 * f1;
  for (int off = 32; off; off >>= 1) s += __shfl_down(s, off);
  if (lane == 0) sq[row] = s;
}

// ---------------------------------------------------------------------------
// fp16 MFMA gram -> distances, triangular 128x128 blocks (bx<=by).
// BOTH orientations computed in registers: acc = A_I·A_J^T (tile I,J) and
// acc2 = A_J·A_I^T (tile J,I) via swapped-operand MFMA — bitwise-identical
// transpose (same k-order, commutative products), so NO LDS restage and all
// global stores are row-contiguous.
// mode 0: de (f32) tiles. mode 1: dz (fp16) tiles + register row-sums.
__global__ __launch_bounds__(256, 2) void gram_kernel(
    const _Float16* __restrict__ He, const float* __restrict__ sqe,
    const _Float16* __restrict__ Hz, const float* __restrict__ sqz,
    float* __restrict__ de, _Float16* __restrict__ dz,
    float* __restrict__ rowsum) {
  __shared__ char smem[65536];
  int b = blockIdx.x;
  int by = (int)((sqrtf(8.0f * (float)b + 1.0f) - 1.0f) * 0.5f);
  while ((by + 1) * (by + 2) / 2 <= b) by++;
  while (by * (by + 1) / 2 > b) by--;
  int bx = b - by * (by + 1) / 2;  // bx <= by
  int mode = blockIdx.z;
  const _Float16* H = mode ? Hz : He;
  const float* sq = mode ? sqz : sqe;
  int I = bx * 128, J = by * 128;
  int t = threadIdx.x;
  bool offd = (bx != by);

  // stage 128 rows x 128 fp16 per side; XOR-swizzle byte ^= (row&7)<<4
#pragma unroll
  for (int it = 0; it < 8; ++it) {
    int u = it * 256 + t;
    int r = u >> 4, c16 = u & 15;
    int byteoff = r * 256 + ((c16 * 16) ^ ((r & 7) << 4));
    *reinterpret_cast<float4*>(smem + byteoff) =
        *reinterpret_cast<const float4*>(H + (size_t)(I + r) * DD + c16 * 8);
    *reinterpret_cast<float4*>(smem + 32768 + byteoff) =
        *reinterpret_cast<const float4*>(H + (size_t)(J + r) * DD + c16 * 8);
  }
  __syncthreads();

  int w = t >> 6, l = t & 63;
  int wr = (w >> 1) * 64, wc = (w & 1) * 64;
  f32x4 acc[4][4], acc2[4][4];
#pragma unroll
  for (int m = 0; m < 4; ++m)
#pragma unroll
    for (int n = 0; n < 4; ++n) {
      f32x4 zz = {0.f, 0.f, 0.f, 0.f};
      acc[m][n] = zz;
      acc2[m][n] = zz;
    }

#pragma unroll
  for (int kstep = 0; kstep < 4; ++kstep) {
    int colb = kstep * 64 + (l >> 4) * 16;
    f16x8 a[4], bb[4];
#pragma unroll
    for (int m = 0; m < 4; ++m) {
      int rr = wr + m * 16 + (l & 15);
      a[m] = *reinterpret_cast<const f16x8*>(smem + rr * 256 + (colb ^ ((rr & 7) << 4)));
    }
#pragma unroll
    for (int n = 0; n < 4; ++n) {
      int rr = wc + n * 16 + (l & 15);
      bb[n] = *reinterpret_cast<const f16x8*>(smem + 32768 + rr * 256 + (colb ^ ((rr & 7) << 4)));
    }
#pragma unroll
    for (int m = 0; m < 4; ++m)
#pragma unroll
      for (int n = 0; n < 4; ++n)
        acc[m][n] = __builtin_amdgcn_mfma_f32_16x16x32_f16(a[m], bb[n], acc[m][n], 0, 0, 0);
    if (offd) {
      f16x8 at[4], bt[4];
#pragma unroll
      for (int n = 0; n < 4; ++n) {
        int rr = wc + n * 16 + (l & 15);
        at[n] = *reinterpret_cast<const f16x8*>(smem + rr * 256 + (colb ^ ((rr & 7) << 4)));
      }
#pragma unroll
      for (int m = 0; m < 4; ++m) {
        int rr = wr + m * 16 + (l & 15);
        bt[m] = *reinterpret_cast<const f16x8*>(smem + 32768 + rr * 256 + (colb ^ ((rr & 7) << 4)));
      }
#pragma unroll
      for (int m = 0; m < 4; ++m)
#pragma unroll
        for (int n = 0; n < 4; ++n)
          acc2[m][n] = __builtin_amdgcn_mfma_f32_16x16x32_f16(bt[m], at[n], acc2[m][n], 0, 0, 0);
    }
  }
  // register-only epilogue — no barrier needed

  if (mode == 0) {
    // ---- de (f32): direct row-contiguous stores, both orientations
#pragma unroll
    for (int m = 0; m < 4; ++m) {
#pragma unroll
      for (int n = 0; n < 4; ++n) {
#pragma unroll
        for (int q = 0; q < 4; ++q) {
          int rt = wr + m * 16 + (l >> 4) * 4 + q;
          int ct = wc + n * 16 + (l & 15);
          int grow = I + rt, gcol = J + ct;
          float d2 = (grow == gcol) ? 0.0f : (sq[grow] + sq[gcol] - 2.0f * acc[m][n][q]);
          float d = __builtin_amdgcn_sqrtf(fmaxf(d2, 0.0f) + 1e-12f);
          de[(size_t)grow * NN + gcol] = d;
          if (offd) {
            int grow2 = J + rt, gcol2 = I + ct;
            float e2 = sq[grow2] + sq[gcol2] - 2.0f * acc2[m][n][q];
            float dT = __builtin_amdgcn_sqrtf(fmaxf(e2, 0.0f) + 1e-12f);
            de[(size_t)grow2 * NN + gcol2] = dT;
          }
        }
      }
    }
  } else {
    // ---- dz (fp16): direct stores + register row-sums
    float rs[16];
    float rs2[16];
#pragma unroll
    for (int u = 0; u < 16; ++u) { rs[u] = 0.0f; rs2[u] = 0.0f; }
#pragma unroll
    for (int m = 0; m < 4; ++m) {
#pragma unroll
      for (int n = 0; n < 4; ++n) {
#pragma unroll
        for (int q = 0; q < 4; ++q) {
          int rt = wr + m * 16 + (l >> 4) * 4 + q;
          int ct = wc + n * 16 + (l & 15);
          int grow = I + rt, gcol = J + ct;
          float d2 = (grow == gcol) ? 0.0f : (sq[grow] + sq[gcol] - 2.0f * acc[m][n][q]);
          float d = __builtin_amdgcn_sqrtf(fmaxf(d2, 0.0f) + 1e-12f);
          d = __builtin_amdgcn_sqrtf(d + 1e-9f);
          _Float16 h = (_Float16)d;
          dz[(size_t)grow * NN + gcol] = h;
          rs[m * 4 + q] += (float)h;
          if (offd) {
            int grow2 = J + rt, gcol2 = I + ct;
            float e2 = sq[grow2] + sq[gcol2] - 2.0f * acc2[m][n][q];
            float dT = __builtin_amdgcn_sqrtf(fmaxf(e2, 0.0f) + 1e-12f);
            dT = __builtin_amdgcn_sqrtf(dT + 1e-9f);
            _Float16 h2 = (_Float16)dT;
            dz[(size_t)grow2 * NN + gcol2] = h2;
            rs2[m * 4 + q] += (float)h2;
          }
        }
      }
    }
    // reduce row partials across the 16 lanes sharing each row
#pragma unroll
    for (int m = 0; m < 4; ++m) {
#pragma unroll
      for (int q = 0; q < 4; ++q) {
        float v = rs[m * 4 + q];
        v += __shfl_xor(v, 1); v += __shfl_xor(v, 2);
        v += __shfl_xor(v, 4); v += __shfl_xor(v, 8);
        if ((l & 15) == 0)
          atomicAdd(&rowsum[I + wr + m * 16 + (l >> 4) * 4 + q], v);
        if (offd) {
          float v2 = rs2[m * 4 + q];
          v2 += __shfl_xor(v2, 1); v2 += __shfl_xor(v2, 2);
          v2 += __shfl_xor(v2, 4); v2 += __shfl_xor(v2, 8);
          if ((l & 15) == 0)
            atomicAdd(&rowsum[J + wr + m * 16 + (l >> 4) * 4 + q], v2);
        }
      }
    }
  }
}

// ---------------------------------------------------------------------------
// fused row pass: stage de-row (f32) + dz-row (fp16) in LDS; top-5(de) ->
// kth; dense partial sum; nbr lists + revcnt. rowmean comes precomputed.
__global__ __launch_bounds__(256) void rowpass_kernel(
    const float* __restrict__ de, const _Float16* __restrict__ dz,
    const float* __restrict__ rowsum, float* __restrict__ rminv,
    int* __restrict__ nbr, int* __restrict__ nbrcnt,
    int* __restrict__ revcnt, double* __restrict__ acc) {
  __shared__ float lde[NN];       // 16 KB
  __shared__ _Float16 ldz[NN];    // 8 KB
  __shared__ double red[256];
  __shared__ float b5[256][5];
  __shared__ float skth;
  __shared__ float sinv;
  __shared__ int scnt;

  int row = blockIdx.x, t = threadIdx.x;
  if (t == 0) {
    scnt = 0;
    float iv = (float)NN / rowsum[row];
    sinv = iv;
    rminv[row] = iv;
  }
  const float4* pe = reinterpret_cast<const float4*>(de + (size_t)row * NN);
  const float4* pz = reinterpret_cast<const float4*>(dz + (size_t)row * NN);
  float best[5] = {3.4e38f, 3.4e38f, 3.4e38f, 3.4e38f, 3.4e38f};
  for (int c = t; c < NN / 8; c += 256) {
    float4 e0 = pe[c * 2];
    float4 e1 = pe[c * 2 + 1];
    float4 vz = pz[c];
    *reinterpret_cast<float4*>(&lde[c * 8]) = e0;
    *reinterpret_cast<float4*>(&lde[c * 8 + 4]) = e1;
    *reinterpret_cast<float4*>(&ldz[c * 8]) = vz;
    float ev[8] = {e0.x, e0.y, e0.z, e0.w, e1.x, e1.y, e1.z, e1.w};
#pragma unroll
    for (int q4 = 0; q4 < 8; ++q4) {
      float v = ev[q4];
      if (v < best[4]) {
        best[4] = v;
#pragma unroll
        for (int q = 4; q > 0; --q)
          if (best[q] < best[q - 1]) {
            float tmp = best[q]; best[q] = best[q - 1]; best[q - 1] = tmp;
          }
      }
    }
  }
#pragma unroll
  for (int q = 0; q < 5; ++q) b5[t][q] = best[q];
  __syncthreads();
  for (int s = 128; s >= 1; s >>= 1) {
    if (t < s) {
      float a[5], b[5], o[5];
#pragma unroll
      for (int q = 0; q < 5; ++q) { a[q] = b5[t][q]; b[q] = b5[t + s][q]; }
      int ia = 0, ib = 0;
#pragma unroll
      for (int q = 0; q < 5; ++q) o[q] = (a[ia] <= b[ib]) ? a[ia++] : b[ib++];
#pragma unroll
      for (int q = 0; q < 5; ++q) b5[t][q] = o[q];
    }
    __syncthreads();
  }
  if (t == 0) skth = b5[0][4];
  __syncthreads();
  float kth = skth, inv = sinv;

  // dense sum + neighbor scan from LDS
  double s = 0.0;
  for (int c = t; c < NN; c += 256) {
    float e = lde[c];
    float del = (float)ldz[c] * inv;
    float rr = fmaxf(1.0f - del, 0.0f);
    float a = del * del - rr * rr;
    s += (double)(0.5f * __expf(-e) * a + rr * rr);
    if (e <= kth) {
      int p = atomicAdd(&scnt, 1);
      if (p < CAPN) nbr[row * CAPN + p] = c;
      atomicAdd(&revcnt[c], 1);
    }
  }
  red[t] = s;
  __syncthreads();
  for (int st = 128; st; st >>= 1) {
    if (t < st) red[t] += red[t + st];
    __syncthreads();
  }
  if (t == 0) {
    atomicAdd(&acc[row & 127], red[0]);
    nbrcnt[row] = min(scnt, CAPN);
  }
}

// ---------------------------------------------------------------------------
// mutual lists: mut[k] = {j : j in kNN(k) and k in kNN(j)}
__global__ __launch_bounds__(64) void mut_kernel(
    const int* __restrict__ nbr, const int* __restrict__ nbrcnt,
    int* __restrict__ mut, int* __restrict__ mutcnt) {
  int k = blockIdx.x;
  int lane = threadIdx.x;
  __shared__ int cnt;
  if (lane == 0) cnt = 0;
  __syncthreads();
  int ck = nbrcnt[k];
  if (lane < ck) {
    int j = nbr[k * CAPN + lane];
    int cj = nbrcnt[j];
    bool found = false;
    for (int q = 0; q < cj; ++q)
      if (nbr[j * CAPN + q] == k) { found = true; break; }
    if (found) {
      int p = atomicAdd(&cnt, 1);
      if (p < CAPM) mut[k * CAPM + p] = j;
    }
  }
  __syncthreads();
  if (lane == 0) mutcnt[k] = min(cnt, CAPM);
}

// ---------------------------------------------------------------------------
// sparse: T = sum_l sum_{i,k in kNN(l)^2} c_i sum_{j in mut(k)} abar[i,j]
__global__ __launch_bounds__(64) void sparse_kernel(
    const int* __restrict__ nbr, const int* __restrict__ nbrcnt,
    const int* __restrict__ revcnt, const int* __restrict__ mut,
    const int* __restrict__ mutcnt, const _Float16* __restrict__ dz,
    const float* __restrict__ rminv, double* __restrict__ acc) {
  int l = blockIdx.x, lane = threadIdx.x;
  int cl = nbrcnt[l];
  int npairs = cl * cl;
  double s = 0.0;
  for (int p = lane; p < npairs; p += 64) {
    int i = nbr[l * CAPN + p / cl];
    int k = nbr[l * CAPN + p % cl];
    float ci = 1.0f / ((float)revcnt[i] * (float)mutcnt[i]);
    float inv_i = rminv[i];
    const _Float16* dzi = dz + (size_t)i * NN;
    int cm = mutcnt[k];
    float ps = 0.0f;
    for (int w2 = 0; w2 < cm; ++w2) {
      int j = mut[k * CAPM + w2];
      float dd = (float)dzi[j];
      float d1 = dd * inv_i;
      float d2v = dd * rminv[j];
      float r1 = fmaxf(1.0f - d1, 0.0f);
      float r2 = fmaxf(1.0f - d2v, 0.0f);
      ps += 0.5f * ((d1 * d1 - r1 * r1) + (d2v * d2v - r2 * r2));
    }
    s += (double)ci * (double)ps;
  }
  for (int off = 32; off; off >>= 1) s += __shfl_down(s, off);
  if (lane == 0) atomicAdd(&acc[128 + (l & 127)], s);
}

// ---------------------------------------------------------------------------
__global__ __launch_bounds__(256) void finalize_kernel(
    const double* __restrict__ acc, float* __restrict__ out) {
  __shared__ double red[256];
  int t = threadIdx.x;
  red[t] = acc[t] * ((t < 128) ? 1.0 : 0.5);
  __syncthreads();
  for (int st = 128; st; st >>= 1) {
    if (t < st) red[t] += red[t + st];
    __syncthreads();
  }
  if (t == 0) out[0] = (float)(red[0] / (double)NN);
}

// ---------------------------------------------------------------------------
extern "C" void kernel_launch(void* const* d_in, const int* in_sizes, int n_in,
                              void* d_out, int out_size, void* d_ws, size_t ws_size,
                              hipStream_t stream) {
  const float* z  = (const float*)d_in[0];
  const float* ze = (const float*)d_in[1];
  float* out = (float*)d_out;

  char* w = (char*)d_ws;
  float* de = (float*)w;                               // 64 MiB f32
  size_t off = (size_t)NN * NN * 4;
  _Float16* dz = (_Float16*)(w + off); off += (size_t)NN * NN * 2;  // 32 MiB
  _Float16* He = (_Float16*)(w + off); off += (size_t)NN * DD * 2;
  _Float16* Hz = (_Float16*)(w + off); off += (size_t)NN * DD * 2;
  float* sqe = (float*)(w + off); off += NN * 4;
  float* sqz = (float*)(w + off); off += NN * 4;
  float* rowsum = (float*)(w + off); off += NN * 4;
  float* rminv = (float*)(w + off); off += NN * 4;
  double* acc = (double*)(w + off); off += 256 * 8;
  int* nbrcnt = (int*)(w + off); off += NN * 4;
  int* mutcnt = (int*)(w + off); off += NN * 4;
  int* revcnt = (int*)(w + off); off += NN * 4;
  int* nbr = (int*)(w + off); off += (size_t)NN * CAPN * 4;
  int* mutl = (int*)(w + off); off += (size_t)NN * CAPM * 4;

  convert_kernel<<<dim3(NN, 2), 64, 0, stream>>>(ze, z, He, Hz, sqe, sqz,
                                                 revcnt, rowsum, acc);
  gram_kernel<<<dim3(NB, 1, 2), 256, 0, stream>>>(He, sqe, Hz, sqz, de, dz,
                                                  rowsum);
  rowpass_kernel<<<NN, 256, 0, stream>>>(de, dz, rowsum, rminv, nbr, nbrcnt,
                                         revcnt, acc);
  mut_kernel<<<NN, 64, 0, stream>>>(nbr, nbrcnt, mutl, mutcnt);
  sparse_kernel<<<NN, 64, 0, stream>>>(nbr, nbrcnt, revcnt, mutl, mutcnt,
                                       dz, rminv, acc);
  finalize_kernel<<<1, 256, 0, stream>>>(acc, out);
}